// Round 1
// baseline (109.618 us; speedup 1.0000x reference)
//
#include <hip/hip_runtime.h>

// Problem constants (fixed by the reference config)
#define BB     2
#define NN     4
#define CC     64
#define HF     64
#define WF     64
#define XVOX   128
#define YVOX   128
#define ZVOX   8
#define BN_TOT (BB * NN)                // 8
#define FEATS_PER_BN (CC * HF * WF)     // 262144 floats
#define OUT_C_STRIDE (ZVOX * XVOX * YVOX)  // 131072
#define OUT_B_STRIDE (CC * OUT_C_STRIDE)   // 8388608

// ---------------------------------------------------------------------------
// Kernel 1: compose per-(b,n) projection matrices.
// mats[bn*12 + 0..3]  = pix row0 (maps ref-space point -> pix x numerator)
// mats[bn*12 + 4..7]  = pix row1
// mats[bn*12 + 8..11] = camX row2 (== pix row2 bitwise; gives z & denom)
// ---------------------------------------------------------------------------
__global__ void prep_mats_kernel(const float* __restrict__ intrins,
                                 const float* __restrict__ extrins,
                                 float* __restrict__ mats) {
    int bn = threadIdx.x;
    if (bn >= BN_TOT) return;
    const float* e = extrins + bn * 16;
    const float* k = intrins + bn * 16;

    // safe_inverse: rT = R^T, t = -R^T t, last row irrelevant for first 3 rows
    float inv[3][4];
#pragma unroll
    for (int i = 0; i < 3; ++i) {
        inv[i][0] = e[0 * 4 + i];
        inv[i][1] = e[1 * 4 + i];
        inv[i][2] = e[2 * 4 + i];
        inv[i][3] = -(e[0 * 4 + i] * e[0 * 4 + 3] +
                      e[1 * 4 + i] * e[1 * 4 + 3] +
                      e[2 * 4 + i] * e[2 * 4 + 3]);
    }
    // scale_intrinsics with sx = sy = 64/512 = 0.125 (exact)
    float fx = k[0] * 0.125f;   // K[0,0]
    float fy = k[5] * 0.125f;   // K[1,1]
    float cx = k[2] * 0.125f;   // K[0,2]
    float cy = k[6] * 0.125f;   // K[1,2]

    float* m = mats + bn * 12;
#pragma unroll
    for (int j = 0; j < 4; ++j) {
        m[j]     = fx * inv[0][j] + cx * inv[2][j];
        m[4 + j] = fy * inv[1][j] + cy * inv[2][j];
        m[8 + j] = inv[2][j];
    }
}

// ---------------------------------------------------------------------------
// Kernel 2: transpose feats NCHW -> NHWC so channels are contiguous.
// One block per (bn, h) row; LDS 64x65 tile kills bank conflicts.
// ---------------------------------------------------------------------------
__global__ __launch_bounds__(256) void transpose_feats_kernel(
    const float* __restrict__ in, float* __restrict__ outT) {
    __shared__ float tile[64 * 65];
    int bh = blockIdx.x;           // bn*64 + h
    int bn = bh >> 6;
    int h  = bh & 63;
    int t  = threadIdx.x;

    const float* src = in + bn * FEATS_PER_BN + h * WF;   // + c*4096 + w
#pragma unroll
    for (int k = 0; k < 16; ++k) {
        int idx = t + k * 256;     // 0..4095
        int c = idx >> 6;
        int w = idx & 63;
        tile[w * 65 + c] = src[c * (HF * WF) + w];        // coalesced read (w fastest)
    }
    __syncthreads();
    float* dst = outT + bn * FEATS_PER_BN + h * (WF * CC);  // + w*64 + c
#pragma unroll
    for (int k = 0; k < 16; ++k) {
        int idx = t + k * 256;
        int w = idx >> 6;
        int c = idx & 63;
        dst[w * CC + c] = tile[w * 65 + c];               // coalesced write (c fastest)
    }
}

// ---------------------------------------------------------------------------
// Kernel 3: main splat. One thread per (b, z, x, y) voxel, y fastest.
// ---------------------------------------------------------------------------
__global__ __launch_bounds__(256) void bev_splat_kernel(
    const float* __restrict__ featsT,   // (BN, H, W, C)
    const float* __restrict__ mats,     // (BN, 12)
    float* __restrict__ out) {
    int tid = blockIdx.x * 256 + threadIdx.x;
    int vy = tid & 127;
    int vx = (tid >> 7) & 127;
    int vz = (tid >> 14) & 7;
    int b  = tid >> 17;

    // mem -> ref-space voxel centers (matches _mem_grid_cam0 in fp32)
    float xc = vx * 0.8f - 50.8f;
    float yc = vy * 0.8f - 50.8f;
    float zc = vz * 0.5f - 2.75f;

    int   offs[4][4];
    float wgt[4][4];
    bool  act[4];

#pragma unroll
    for (int n = 0; n < NN; ++n) {
        int bn = b * NN + n;
        const float* M = mats + bn * 12;
        float px = M[0] * xc + M[1] * yc + M[2]  * zc + M[3];
        float py = M[4] * xc + M[5] * yc + M[6]  * zc + M[7];
        float pz = M[8] * xc + M[9] * yc + M[10] * zc + M[11];
        float denom = fmaxf(pz, 1e-6f);
        float sx = px / denom;
        float sy = py / denom;
        bool valid = (sx > -0.5f) && (sx < (float)WF - 0.5f) &&
                     (sy > -0.5f) && (sy < (float)HF - 0.5f) && (pz > 0.0f);
        act[n] = valid;
        int base = bn * FEATS_PER_BN;
        if (valid) {
            float gx = sx - 0.5f;
            float gy = sy - 0.5f;
            float x0f = floorf(gx), y0f = floorf(gy);
            float wx = gx - x0f,    wy = gy - y0f;
            int x0 = (int)x0f, y0 = (int)y0f;
            int xs[2]  = {x0, x0 + 1};
            int ys[2]  = {y0, y0 + 1};
            float wxs[2] = {1.0f - wx, wx};
            float wys[2] = {1.0f - wy, wy};
#pragma unroll
            for (int ky = 0; ky < 2; ++ky) {
#pragma unroll
                for (int kx = 0; kx < 2; ++kx) {
                    int kk = ky * 2 + kx;   // corner order matches reference sum order
                    int xi = xs[kx], yi = ys[ky];
                    bool cv = (xi >= 0) && (xi < WF) && (yi >= 0) && (yi < HF);
                    int xic = min(max(xi, 0), WF - 1);
                    int yic = min(max(yi, 0), HF - 1);
                    offs[n][kk] = base + (yic * WF + xic) * CC;
                    wgt[n][kk]  = cv ? (wxs[kx] * wys[ky]) : 0.0f;
                }
            }
        } else {
#pragma unroll
            for (int kk = 0; kk < 4; ++kk) { offs[n][kk] = base; wgt[n][kk] = 0.0f; }
        }
    }

    int out_base = b * OUT_B_STRIDE + vz * (XVOX * YVOX) + vx * YVOX + vy;

    if (!(act[0] || act[1] || act[2] || act[3])) {
        // sum=0, count=0 -> 0/(1e-6) = 0 for every channel
#pragma unroll
        for (int c = 0; c < CC; ++c) out[out_base + c * OUT_C_STRIDE] = 0.0f;
        return;
    }

#pragma unroll 4
    for (int c4 = 0; c4 < CC / 4; ++c4) {
        float num0 = 0.f, num1 = 0.f, num2 = 0.f, num3 = 0.f;
        float cnt0 = 0.f, cnt1 = 0.f, cnt2 = 0.f, cnt3 = 0.f;
#pragma unroll
        for (int n = 0; n < NN; ++n) {
            if (!act[n]) continue;
            float v0 = 0.f, v1 = 0.f, v2 = 0.f, v3 = 0.f;
#pragma unroll
            for (int kk = 0; kk < 4; ++kk) {
                const float4 g =
                    *reinterpret_cast<const float4*>(featsT + offs[n][kk] + c4 * 4);
                float w = wgt[n][kk];
                v0 += w * g.x; v1 += w * g.y; v2 += w * g.z; v3 += w * g.w;
            }
            num0 += v0; num1 += v1; num2 += v2; num3 += v3;
            cnt0 += (v0 != 0.0f) ? 1.0f : 0.0f;
            cnt1 += (v1 != 0.0f) ? 1.0f : 0.0f;
            cnt2 += (v2 != 0.0f) ? 1.0f : 0.0f;
            cnt3 += (v3 != 0.0f) ? 1.0f : 0.0f;
        }
        int c0 = c4 * 4;
        out[out_base + (c0 + 0) * OUT_C_STRIDE] = num0 / (1e-6f + cnt0);
        out[out_base + (c0 + 1) * OUT_C_STRIDE] = num1 / (1e-6f + cnt1);
        out[out_base + (c0 + 2) * OUT_C_STRIDE] = num2 / (1e-6f + cnt2);
        out[out_base + (c0 + 3) * OUT_C_STRIDE] = num3 / (1e-6f + cnt3);
    }
}

// ---------------------------------------------------------------------------
extern "C" void kernel_launch(void* const* d_in, const int* in_sizes, int n_in,
                              void* d_out, int out_size, void* d_ws, size_t ws_size,
                              hipStream_t stream) {
    const float* feats   = (const float*)d_in[0];   // (2,4,64,64,64)
    const float* intrins = (const float*)d_in[1];   // (2,4,4,4)
    const float* extrins = (const float*)d_in[2];   // (2,4,4,4)
    float* out = (float*)d_out;                     // (2,512,128,128)

    float* featsT = (float*)d_ws;                         // 8 * 262144 floats = 8 MB
    float* mats   = featsT + BN_TOT * FEATS_PER_BN;       // 8 * 12 floats

    prep_mats_kernel<<<1, 64, 0, stream>>>(intrins, extrins, mats);
    transpose_feats_kernel<<<BN_TOT * HF, 256, 0, stream>>>(feats, featsT);

    int total = BB * ZVOX * XVOX * YVOX;   // 262144 threads
    bev_splat_kernel<<<total / 256, 256, 0, stream>>>(featsT, mats, out);
}